// Round 7
// baseline (994.706 us; speedup 1.0000x reference)
//
#include <hip/hip_runtime.h>
#include <hip/hip_bf16.h>
#include <cstddef>
#include <cstdint>

#define NNODE  20000
#define MPAD   20096        // 314*64
#define NEDGE  240000
#define NGRAPH 200
#define DIN    118
#define HD     256
#define NBASIS 10
#define RHID   100
#define NLAYER 3
#define NSH    9
#define SHSTR  16           // sh row stride in f16 (32 B); [8]=Y8, [10..11]=src bits
#define KTP    (NSH * HD)   // 2304
#define KTOT   (KTP + HD)   // 2560
#define KR2    128          // padded radial K
#define KEMB   128          // padded embed K (118 -> 128)
#define NRT    (MPAD / 64)       // 314 row tiles

typedef _Float16 f16;
typedef _Float16 f16x2 __attribute__((ext_vector_type(2)));
typedef _Float16 f16x4 __attribute__((ext_vector_type(4)));
typedef _Float16 f16x8 __attribute__((ext_vector_type(8)));
typedef float    f32x4 __attribute__((ext_vector_type(4)));

__device__ __forceinline__ float gelu_tanh(float v) {
  float v3 = v * v * v;
  return 0.5f * v * (1.f + tanhf(0.7978845608028654f * (v + 0.044715f * v3)));
}

// async global->LDS 16B: LDS dest is wave-uniform base + lane*16 (HW rule)
__device__ __forceinline__ void gload16(const void* g, void* l) {
  __builtin_amdgcn_global_load_lds(
      (const __attribute__((address_space(1))) unsigned int*)g,
      (__attribute__((address_space(3))) unsigned int*)l, 16, 0, 0);
}

// within 64-group: physical row rho holds true column perm(rho)
__device__ __forceinline__ int perm64(int rho) {
  return (rho & ~63) | ((rho & 15) * 4 + ((rho >> 4) & 3));
}
__device__ __forceinline__ int inv_perm64(int n) {
  return (n & ~63) | (((n & 3) << 4) | ((n >> 2) & 15));
}

// ---------------- CSR build ----------------
__global__ void deg_hist_kernel(const int* __restrict__ ei, int* __restrict__ deg)
{
  int e = blockIdx.x * 256 + threadIdx.x;
  if (e >= NEDGE) return;
  atomicAdd(&deg[ei[NEDGE + e]], 1);
}

__global__ void scan_kernel(const int* __restrict__ deg, int* __restrict__ rowptr)
{
  __shared__ int part[256];
  int t = threadIdx.x;
  const int chunk = (NNODE + 255) / 256;
  int start = t * chunk;
  int end = min(start + chunk, NNODE);
  int s = 0;
  for (int i = start; i < end; ++i) s += deg[i];
  part[t] = s;
  __syncthreads();
  for (int off = 1; off < 256; off <<= 1) {
    int v = (t >= off) ? part[t - off] : 0;
    __syncthreads();
    part[t] += v;
    __syncthreads();
  }
  int run = (t == 0) ? 0 : part[t - 1];
  for (int i = start; i < end; ++i) { rowptr[i] = run; run += deg[i]; }
  if (t == 255) rowptr[NNODE] = run;
}

// ------- node groups: consecutive nodes, <=64 edges AND <=7 nodes -------
// (<=7 nodes so M = 9*nodes <= 63 fits one 64-row MFMA tile in the fused
// gather.) Greedy within per-thread chunks.
__global__ void group_build_kernel(const int* __restrict__ rowptr,
                                   int* __restrict__ grp_start,
                                   int* __restrict__ n_groups)
{
  __shared__ int cnts[256];
  int t = threadIdx.x;
  const int chunk = (NNODE + 255) / 256;   // 79
  int nbeg = t * chunk;
  int nend = min(nbeg + chunk, NNODE);
  // pass 1: count groups
  int cnt = 0;
  if (nbeg < nend) {
    int ebase = rowptr[nbeg];
    int gstart = nbeg;
    for (int n = nbeg; n < nend; ++n) {
      if (rowptr[n + 1] - ebase > 64 || n - gstart >= 7) {
        ++cnt; ebase = rowptr[n]; gstart = n;
      }
    }
    ++cnt;
  }
  cnts[t] = cnt;
  __syncthreads();
  for (int off = 1; off < 256; off <<= 1) {
    int v = (t >= off) ? cnts[t - off] : 0;
    __syncthreads();
    cnts[t] += v;
    __syncthreads();
  }
  int g = (t == 0) ? 0 : cnts[t - 1];
  // pass 2: emit
  if (nbeg < nend) {
    int ebase = rowptr[nbeg];
    int gstart = nbeg;
    for (int n = nbeg; n < nend; ++n) {
      if (rowptr[n + 1] - ebase > 64 || n - gstart >= 7) {
        grp_start[g++] = gstart;
        gstart = n;
        ebase = rowptr[n];
      }
    }
    grp_start[g++] = gstart;
  }
  if (t == 255) { grp_start[cnts[255]] = NNODE; *n_groups = cnts[255]; }
}

// -------- edge geometry + scatter into CSR (dst-sorted) position --------
__global__ void edge_geom_kernel(const float* __restrict__ pos,
                                 const float* __restrict__ shift,
                                 const float* __restrict__ lat,
                                 const int* __restrict__ ei,
                                 const int* __restrict__ batch,
                                 const int* __restrict__ rowptr,
                                 int* __restrict__ cursor,
                                 f16* __restrict__ sh_s,
                                 float* __restrict__ lens_s)
{
  int e = blockIdx.x * 256 + threadIdx.x;
  if (e >= NEDGE) return;
  int src = ei[e];
  int dst = ei[NEDGE + e];
  int b = batch[src];
  const float* L = lat + (size_t)b * 9;
  float s0 = shift[e * 3 + 0], s1 = shift[e * 3 + 1], s2 = shift[e * 3 + 2];
  float ev[3];
#pragma unroll
  for (int j = 0; j < 3; ++j)
    ev[j] = pos[dst * 3 + j] - pos[src * 3 + j] + s0 * L[j] + s1 * L[3 + j] + s2 * L[6 + j];
  float len = sqrtf(ev[0] * ev[0] + ev[1] * ev[1] + ev[2] * ev[2]);
  float inv = 1.f / (len + 1e-12f);
  float x = ev[0] * inv, y = ev[1] * inv, z = ev[2] * inv;
  const float c1 = 1.7320508075688772f;   // sqrt(3)
  const float c2 = 3.872983346207417f;    // sqrt(15)
  int p = atomicAdd(&cursor[dst], 1);
  int si = rowptr[dst] + p;
  f16* she = sh_s + (size_t)si * SHSTR;
  she[0] = (f16)1.f;
  she[1] = (f16)(c1 * x);
  she[2] = (f16)(c1 * y);
  she[3] = (f16)(c1 * z);
  she[4] = (f16)(c2 * x * y);
  she[5] = (f16)(c2 * y * z);
  she[6] = (f16)(1.1180339887498949f * (3.f * z * z - 1.f));  // sqrt(5)/2
  she[7] = (f16)(c2 * x * z);
  she[8] = (f16)(1.9364916731037085f * (x * x - y * y));      // sqrt(15)/2
  she[9] = (f16)0.f;
  *(int*)(she + 10) = src;            // src bits in slots 10-11 (4B-aligned)
  she[12] = (f16)0.f; she[13] = (f16)0.f; she[14] = (f16)0.f; she[15] = (f16)0.f;
  lens_s[si] = len;
}

// ---------------- merged per-layer weight prep ----------------
__global__ void prep_kernel(const float* __restrict__ Wtp_l,
                            const float* __restrict__ Wself_l,
                            const float* __restrict__ Wskip_l,
                            const float* __restrict__ r2l,
                            const float* __restrict__ r1l,
                            const float* __restrict__ b1l,
                            f16* __restrict__ Wtp16,
                            f16* __restrict__ WselfT16,
                            f16* __restrict__ Bcat,
                            f16* __restrict__ r2h,
                            f16* __restrict__ r1h)
{
  int b = blockIdx.x, t = threadIdx.x;
  if (b < KTP) {
    int i = b * 256 + t;
    Wtp16[i] = (f16)Wtp_l[i];
  } else if (b < KTP + 256) {
    int n = b - KTP;
    WselfT16[(size_t)n * HD + t] = (f16)(Wself_l[(size_t)t * HD + n] * 0.28867513459481287f);
  } else if (b < KTP + 512) {
    int rho = b - KTP - 256;            // physical (permuted) Bcat row
    int pcol = perm64(rho);             // true column it holds
    Bcat[(size_t)rho * KTOT + KTP + t] = (f16)Wskip_l[(size_t)t * HD + pcol];
  } else if (b < KTP + 768) {
    int rho = b - KTP - 512;
    if (t < KR2) {
      int p = perm64(rho);
      r2h[(size_t)rho * KR2 + t] = (t < RHID) ? (f16)r2l[(size_t)t * HD + p] : (f16)0.f;
    }
  } else {
    // r1h [128][32] f16, n-major: col j<NBASIS = r1[j][n]; j==NBASIS = bias; else 0.
#pragma unroll
    for (int u = 0; u < 16; ++u) {
      int idx = u * 256 + t;
      int n = idx >> 5, j = idx & 31;
      float v = 0.f;
      if (n < RHID) {
        if (j < NBASIS) v = r1l[(size_t)j * RHID + n];
        else if (j == NBASIS) v = b1l[n];
      }
      r1h[idx] = (f16)v;
    }
  }
}

// -------- embed conversions --------
__global__ void convert_x_kernel(const float* __restrict__ x, f16* __restrict__ xh)
{
  int i = blockIdx.x * 2 + (threadIdx.x >> 7);
  int k = threadIdx.x & 127;
  xh[(size_t)i * KEMB + k] = (i < NNODE && k < DIN) ? (f16)x[(size_t)i * DIN + k] : (f16)0.f;
}

__global__ void convert_wemb_kernel(const float* __restrict__ Wemb, f16* __restrict__ WembT16)
{
  int n = blockIdx.x, k = threadIdx.x;
  WembT16[(size_t)n * KEMB + k] = (k < DIN) ? (f16)Wemb[(size_t)k * HD + n] : (f16)0.f;
}

// small MFMA GEMM: C[M][ldc] = A[M][K] @ B^T, B n-major [N][K].
// permRows: store output row r at physical row inv_perm64(r) (for permuted Bcat).
__global__ __launch_bounds__(256) void gemm_nt_kernel(
    const f16* __restrict__ A, const f16* __restrict__ B,
    f16* __restrict__ C, int K, int ldc, int permRows)
{
  __shared__ __align__(16) f16 As[4][64][8];
  __shared__ __align__(16) f16 Bs[4][128][8];
  int t = threadIdx.x;
  int lane = t & 63, w = t >> 6;
  int row0 = blockIdx.x * 64;
  int n0 = blockIdx.y * 128;
  f32x4 acc[2][4];
#pragma unroll
  for (int i = 0; i < 2; ++i)
#pragma unroll
    for (int j = 0; j < 4; ++j) acc[i][j] = (f32x4){0.f, 0.f, 0.f, 0.f};
  int mq = (w & 1) * 32, nq = (w >> 1) * 64;
  for (int k0 = 0; k0 < K; k0 += 32) {
    {
      int row = t & 63, cc = t >> 6;
      *(uint4*)&As[cc][row][0] = *(const uint4*)(A + (size_t)(row0 + row) * K + k0 + cc * 8);
    }
#pragma unroll
    for (int u = 0; u < 2; ++u) {
      int idx = t + u * 256;
      int ch = idx >> 7, nn = idx & 127;
      *(uint4*)&Bs[ch][nn][0] = *(const uint4*)(B + (size_t)(n0 + nn) * K + k0 + ch * 8);
    }
    __syncthreads();
    int q = lane >> 4, r = lane & 15;
    f16x8 af[2], bfr[4];
#pragma unroll
    for (int i = 0; i < 2; ++i) af[i] = *(const f16x8*)&As[q][mq + i * 16 + r][0];
#pragma unroll
    for (int j = 0; j < 4; ++j) bfr[j] = *(const f16x8*)&Bs[q][nq + j * 16 + r][0];
#pragma unroll
    for (int i = 0; i < 2; ++i)
#pragma unroll
      for (int j = 0; j < 4; ++j)
        acc[i][j] = __builtin_amdgcn_mfma_f32_16x16x32_f16(af[i], bfr[j], acc[i][j], 0, 0, 0);
    __syncthreads();
  }
  int q4 = ((lane >> 4)) * 4, cl = lane & 15;
#pragma unroll
  for (int i = 0; i < 2; ++i)
#pragma unroll
    for (int rr = 0; rr < 4; ++rr) {
      int row = row0 + mq + i * 16 + q4 + rr;
      int orow = permRows ? inv_perm64(row) : row;
#pragma unroll
      for (int j = 0; j < 4; ++j)
        C[(size_t)orow * ldc + n0 + nq + j * 16 + cl] = (f16)acc[i][j][rr];
    }
}

// ------- fused radial MLP + h[src] multiply + MFMA gather -> T -------
// v2: gather via masked matmul. W[m][e] = sh[e][a] (m = local_node*9 + a,
// zero-padded) built in LDS; hs written TRANSPOSED (hs_t[c][e], perm64'd
// channel rows for free f16x4 T-packing); T_group[64][256] = W @ hs_t^T via
// 32 MFMA/wave. Replaces the serial per-node VALU loop (~700 inst/thread,
// 44% VALUBusy, MfmaUtil 6.7%) that made v1 (118 us) slower than the
// unfused pair (94 us).
#define RHSTR 136   // rhA stride (272 B)
#define ESTE  66    // hs_t / W row stride in f16 (132 B -> ~2-way banks)
__global__ __launch_bounds__(256, 3) void radial_gather_kernel(
    const int* __restrict__ rowptr,
    const int* __restrict__ grp_start,
    const int* __restrict__ n_groups,
    const float* __restrict__ lens_s,
    const f16* __restrict__ sh_s,
    const f16* __restrict__ h,
    const f16* __restrict__ r1h,      // [128][32] f16 n-major (bias j=10)
    const f16* __restrict__ r2h,      // [256][128] f16 perm64 rows
    f16* __restrict__ T)
{
  // smem: [0, 33792) = union(emb_s[64][40] + rhA[64][RHSTR], hs_t[256][ESTE])
  //       [33792, 42240) = W[64][ESTE]
  __shared__ __align__(16) char smem[(256 + 64) * ESTE * 2];   // 42240 B
  __shared__ __align__(16) f16 shL[64][16];                    // 2 KB
  __shared__ int srcs[64];
  __shared__ int ln_s[64];
  __shared__ signed char m2n_s[64];
  __shared__ signed char m2a_s[64];
  f16* emb_s = (f16*)smem;                       // [64][40]
  f16* rhA   = (f16*)(smem + 64 * 40 * 2);       // [64][RHSTR]
  f16* hs_t  = (f16*)smem;                       // [256][ESTE]
  f16* Wp    = (f16*)(smem + 256 * ESTE * 2);    // [64][ESTE]

  int t = threadIdx.x;
  int lane = t & 63, w = t >> 6;
  int r = lane & 15, q = lane >> 4;
  int n0w = w * 64;

  // group-invariant B fragments (L2-resident)
  f16x8 bfr[4][4];
#pragma unroll
  for (int j = 0; j < 4; ++j)
#pragma unroll
    for (int ks = 0; ks < 4; ++ks)
      bfr[j][ks] = *(const f16x8*)(r2h + (size_t)(n0w + j * 16 + r) * KR2 + ks * 32 + q * 8);
  f16x8 b1f[2];
#pragma unroll
  for (int j = 0; j < 2; ++j)
    b1f[j] = *(const f16x8*)(r1h + (size_t)((2 * w + j) * 16 + r) * 32 + q * 8);

  int ng = *n_groups;
  for (int g = blockIdx.x; g < ng; g += gridDim.x) {
    int gn0 = grp_start[g], gn1 = grp_start[g + 1];
    int ebeg = rowptr[gn0];
    int ecnt = rowptr[gn1] - ebeg;   // <= 64

    // ---- staging phase (W region free until gather; zero it here) ----
    {
      uint4 z = {0u, 0u, 0u, 0u};
#pragma unroll
      for (int u = 0; u < 3; ++u) {
        int idx = u * 256 + t;
        if (idx < (64 * ESTE * 2) / 16) ((uint4*)Wp)[idx] = z;
      }
    }
    {
      int e = ebeg + (t >> 2); if (e >= NEDGE) e = NEDGE - 1;
      *(f16x4*)&shL[t >> 2][(t & 3) * 4] = *(const f16x4*)(sh_s + (size_t)e * SHSTR + (t & 3) * 4);
    }
    if (t < 64) {
      int e = ebeg + t; if (e >= NEDGE) e = NEDGE - 1;
      srcs[t] = *(const int*)(sh_s + (size_t)e * SHSTR + 10);
      int ln = 0;
      while (gn0 + ln + 1 < gn1 && ebeg + t >= rowptr[gn0 + ln + 1]) ++ln;
      ln_s[t] = ln;
      int nn = gn1 - gn0;
      m2n_s[t] = (t < 9 * nn) ? (signed char)(t / 9) : (signed char)(-1);
      m2a_s[t] = (signed char)(t % 9);
    }

    // basis: thread (w,lane) -> emb_s[lane][w*8 .. w*8+7]
    {
      int le = ebeg + lane; if (le >= NEDGE) le = NEDGE - 1;
      float len = lens_s[le];
      const float step = 5.f / 11.f;
      const float sq = 3.1622776601683795f;   // sqrt(10)
      f16x8 v;
#pragma unroll
      for (int kk = 0; kk < 8; ++kk) {
        int j = w * 8 + kk;
        float val = 0.f;
        if (j < NBASIS) {
          float d = (len - (float)(j + 1) * step) / step;
          val = (d > -1.f && d < 1.f) ? (__cosf(1.5707963267948966f * d) * sq) : 0.f;
        } else if (j == NBASIS) {
          val = 1.f;
        }
        v[kk] = (f16)val;
      }
      *(f16x8*)&emb_s[lane * 40 + w * 8] = v;
    }
    __syncthreads();   // (1) emb/shL/srcs/ln/m2* ready, W zeroed

    // W build: W[ln*9+a][e] = sh[e][a]  (4 threads per edge)
    {
      int e = t >> 2, p = t & 3;
      if (e < ecnt) {
        int mb = ln_s[e] * 9;
        Wp[(mb + p) * ESTE + e]     = shL[e][p];
        Wp[(mb + 4 + p) * ESTE + e] = shL[e][4 + p];
        if (p == 0) Wp[(mb + 8) * ESTE + e] = shL[e][8];
      }
    }

    // layer-1 MFMA: rh[64][128] = emb[64][32] @ r1h^T
    f32x4 acc1[4][2];
#pragma unroll
    for (int i = 0; i < 4; ++i)
#pragma unroll
      for (int j = 0; j < 2; ++j) acc1[i][j] = (f32x4){0.f, 0.f, 0.f, 0.f};
    {
      f16x8 a1f[4];
#pragma unroll
      for (int i = 0; i < 4; ++i)
        a1f[i] = *(const f16x8*)&emb_s[(i * 16 + r) * 40 + q * 8];
#pragma unroll
      for (int i = 0; i < 4; ++i)
#pragma unroll
        for (int j = 0; j < 2; ++j)
          acc1[i][j] = __builtin_amdgcn_mfma_f32_16x16x32_f16(a1f[i], b1f[j], acc1[i][j], 0, 0, 0);
    }

    // silu -> rhA. value (i,j,rr): row=i*16+q*4+rr, col=(2w+j)*16+r
#pragma unroll
    for (int i = 0; i < 4; ++i)
#pragma unroll
      for (int j = 0; j < 2; ++j)
#pragma unroll
        for (int rr = 0; rr < 4; ++rr) {
          float s = acc1[i][j][rr];
          s = __fdividef(s, 1.f + __expf(-s));
          rhA[(i * 16 + q * 4 + rr) * RHSTR + (2 * w + j) * 16 + r] = (f16)s;
        }
    __syncthreads();   // (2) rhA + W ready

    // h[src] frags: 16 coalesced f16x4 L2 loads, latency hides under MFMA
    f16x4 hv[4][4];
#pragma unroll
    for (int i = 0; i < 4; ++i)
#pragma unroll
      for (int rr = 0; rr < 4; ++rr) {
        int m = i * 16 + q * 4 + rr;
        hv[i][rr] = *(const f16x4*)(h + (size_t)srcs[m] * HD + n0w + r * 4);
      }

    // layer-2 MFMA: radial[64,256] = rh[64,128] @ r2h_perm^T
    f32x4 acc[4][4];
#pragma unroll
    for (int i = 0; i < 4; ++i)
#pragma unroll
      for (int j = 0; j < 4; ++j) acc[i][j] = (f32x4){0.f, 0.f, 0.f, 0.f};
#pragma unroll
    for (int ks = 0; ks < 4; ++ks) {
      f16x8 af[4];
#pragma unroll
      for (int i = 0; i < 4; ++i)
        af[i] = *(const f16x8*)&rhA[(i * 16 + r) * RHSTR + ks * 32 + q * 8];
#pragma unroll
      for (int i = 0; i < 4; ++i)
#pragma unroll
        for (int j = 0; j < 4; ++j)
          acc[i][j] = __builtin_amdgcn_mfma_f32_16x16x32_f16(af[i], bfr[j][ks], acc[i][j], 0, 0, 0);
    }
    __syncthreads();   // (3) rhA consumed; safe to overlay hs_t

    // hs_t[c][e] = rad*h[src], TRANSPOSED, perm64 channel rows:
    // value (i,j,rr) = edge m, true ch n0w+r*4+j -> physical row n0w+j*16+r
#pragma unroll
    for (int i = 0; i < 4; ++i)
#pragma unroll
      for (int j = 0; j < 4; ++j)
#pragma unroll
        for (int rr = 0; rr < 4; ++rr) {
          int m = i * 16 + q * 4 + rr;
          hs_t[(n0w + j * 16 + r) * ESTE + m] =
              (f16)(acc[i][j][rr] * (float)hv[i][rr][j]);
        }
    __syncthreads();   // (4) hs_t ready

    // gather MFMA: out[64][256] = W[64][64] @ hs_t^T (wave w: its 64 channels)
    f32x4 og[4][4];
#pragma unroll
    for (int i = 0; i < 4; ++i)
#pragma unroll
      for (int j = 0; j < 4; ++j) og[i][j] = (f32x4){0.f, 0.f, 0.f, 0.f};
#pragma unroll
    for (int ks = 0; ks < 2; ++ks) {
      f16x8 af[4], bf[4];
#pragma unroll
      for (int i = 0; i < 4; ++i)
        af[i] = *(const f16x8*)&Wp[(i * 16 + r) * ESTE + ks * 32 + q * 8];
#pragma unroll
      for (int j = 0; j < 4; ++j)
        bf[j] = *(const f16x8*)&hs_t[(n0w + j * 16 + r) * ESTE + ks * 32 + q * 8];
#pragma unroll
      for (int i = 0; i < 4; ++i)
#pragma unroll
        for (int j = 0; j < 4; ++j)
          og[i][j] = __builtin_amdgcn_mfma_f32_16x16x32_f16(af[i], bf[j], og[i][j], 0, 0, 0);
    }

    // T store: row m -> (node, a); col n-idx j*16+cl -> true ch cl*4+j (packed)
#pragma unroll
    for (int i = 0; i < 4; ++i)
#pragma unroll
      for (int rr = 0; rr < 4; ++rr) {
        int m = i * 16 + q * 4 + rr;
        int nd = m2n_s[m];
        if (nd >= 0) {
          int a = m2a_s[m];
          f16x4 o;
#pragma unroll
          for (int j = 0; j < 4; ++j) o[j] = (f16)og[i][j][rr];
          *(f16x4*)(T + (size_t)(gn0 + nd) * KTP + a * HD + n0w + r * 4) = o;
        }
      }
    __syncthreads();   // (5) protect smem reuse by next group
  }
}

// ------- fused full-K MFMA GEMM + gelu epilogue -------
// R2 schedule+layout (fastest measured variant of this structure).
#define GBM 64
#define GBN 128
#define NKSTEP (KTOT / 32)    // 80
__global__ __launch_bounds__(256) void gemm_fused_kernel(
    const f16* __restrict__ A1,   // T [MPAD][2304]
    const f16* __restrict__ A2,   // h [MPAD][256]
    const f16* __restrict__ B,    // Bcat [256][2560] (n-major, perm64 rows)
    f16* __restrict__ C)          // h_next [MPAD][256]
{
  __shared__ __align__(16) f16 As[2][GBM][4][8];   //  8 KB
  __shared__ __align__(16) f16 Bs[2][GBN][4][8];   // 16 KB
  int t = threadIdx.x;
  int lane = t & 63, w = t >> 6;
  int row0 = blockIdx.x * GBM;
  int n0 = blockIdx.y * GBN;
  int mq = (w & 1) * 32, nq = (w >> 1) * 64;
  int arow = t >> 2, ach = t & 3;

  f32x4 acc[2][4];
#pragma unroll
  for (int i = 0; i < 2; ++i)
#pragma unroll
    for (int j = 0; j < 4; ++j) acc[i][j] = (f32x4){0.f, 0.f, 0.f, 0.f};

  auto stage = [&](int buf, int k0) {
    const f16* ga = (k0 < KTP)
        ? (A1 + (size_t)(row0 + arow) * KTP + k0 + ach * 8)
        : (A2 + (size_t)(row0 + arow) * HD + (k0 - KTP) + ach * 8);
    gload16(ga, &As[buf][0][0][0] + (size_t)w * 512);
#pragma unroll
    for (int u = 0; u < 2; ++u) {
      int idx = t + u * 256;
      const f16* gb = B + (size_t)(n0 + (idx >> 2)) * KTOT + k0 + (idx & 3) * 8;
      gload16(gb, &Bs[buf][0][0][0] + (size_t)(u * 256 + w * 64) * 8);
    }
  };

  stage(0, 0);
  __syncthreads();   // buf0 ready

  int cur = 0;
  int q = lane >> 4, r = lane & 15;
  for (int s = 0; s < NKSTEP; ++s) {
    if (s + 1 < NKSTEP) stage(cur ^ 1, (s + 1) * 32);
    f16x8 af[2], bfr[4];
#pragma unroll
    for (int i = 0; i < 2; ++i) af[i] = *(const f16x8*)&As[cur][mq + i * 16 + r][q][0];
#pragma unroll
    for (int j = 0; j < 4; ++j) bfr[j] = *(const f16x8*)&Bs[cur][nq + j * 16 + r][q][0];
#pragma unroll
    for (int i = 0; i < 2; ++i)
#pragma unroll
      for (int j = 0; j < 4; ++j)
        acc[i][j] = __builtin_amdgcn_mfma_f32_16x16x32_f16(af[i], bfr[j], acc[i][j], 0, 0, 0);
    __syncthreads();   // drains vmcnt: stage(s+1) landed; reads of buf[cur] done
    cur ^= 1;
  }

  // permuted-B gelu epilogue: MFMA n-index j*16+cl -> true col cl*4+j
  int q4 = (lane >> 4) * 4, cl = lane & 15;
#pragma unroll
  for (int i = 0; i < 2; ++i)
#pragma unroll
    for (int rr = 0; rr < 4; ++rr) {
      int row = row0 + mq + i * 16 + q4 + rr;   // MPAD-padded: no guard
      f16x4 o;
#pragma unroll
      for (int j = 0; j < 4; ++j) o[j] = (f16)gelu_tanh(acc[i][j][rr]);
      *(f16x4*)(C + (size_t)row * HD + n0 + nq + cl * 4) = o;
    }
}

// ---------------- node_out fused with graph mean (no atomics) ----------------
__global__ __launch_bounds__(256) void node_out_fused_kernel(
    const f16* __restrict__ h,
    const float* __restrict__ Wout,
    const int* __restrict__ batch,
    float* __restrict__ out)
{
  __shared__ float red[256];
  int g = blockIdx.x;
  int t = threadIdx.x;
  int lo = 0, hi = NNODE;
  while (lo < hi) { int mid = (lo + hi) >> 1; if (batch[mid] < g) lo = mid + 1; else hi = mid; }
  int start = lo;
  hi = NNODE;
  while (lo < hi) { int mid = (lo + hi) >> 1; if (batch[mid] < g + 1) lo = mid + 1; else hi = mid; }
  int end = lo;
  int half = t >> 7, lc = t & 127;
  float a0 = 0.f, a1 = 0.f;
  for (int n = start + half; n < end; n += 2) {
    f16x2 v = *(const f16x2*)(h + (size_t)n * HD + 2 * lc);
    a0 += (float)v[0];
    a1 += (float)v[1];
  }
  red[t] = a0 * Wout[2 * lc] + a1 * Wout[2 * lc + 1];
  for (int off = 128; off > 0; off >>= 1) {
    __syncthreads();
    if (t < off) red[t] += red[t + off];
  }
  if (t == 0) out[g] = red[0] / fmaxf((float)(end - start), 1.f);
}

// ---------------- host launch ----------------
extern "C" void kernel_launch(void* const* d_in, const int* in_sizes, int n_in,
                              void* d_out, int out_size, void* d_ws, size_t ws_size,
                              hipStream_t stream)
{
  (void)in_sizes; (void)n_in; (void)out_size;
  const float* x     = (const float*)d_in[0];
  const float* pos   = (const float*)d_in[1];
  const float* shift = (const float*)d_in[2];
  const float* lat   = (const float*)d_in[3];
  const float* Wemb  = (const float*)d_in[4];
  const float* r1    = (const float*)d_in[5];
  const float* b1    = (const float*)d_in[6];
  const float* r2    = (const float*)d_in[7];
  const float* Wtp   = (const float*)d_in[8];
  const float* Wself = (const float*)d_in[9];
  const float* Wskip = (const float*)d_in[10];
  const float* Wout  = (const float*)d_in[11];
  const int*   eidx  = (const int*)d_in[12];
  const int*   batch = (const int*)d_in[13];
  float* out = (float*)d_out;

  char* ws = (char*)d_ws;
  size_t off = 0;
  auto alloc = [&](size_t bytes) -> char* {
    char* p = ws + off;
    off += (bytes + 255) & ~(size_t)255;
    return p;
  };
  f16*   sh_s    = (f16*)alloc((size_t)NEDGE * SHSTR * 2);      //   7.68 MB
  float* lens_s  = (float*)alloc((size_t)NEDGE * 4);            //   0.96 MB
  f16*   hA      = (f16*)alloc((size_t)MPAD * HD * 2);          //  10.29 MB
  f16*   hB      = (f16*)alloc((size_t)MPAD * HD * 2);          //  10.29 MB
  f16*   T       = (f16*)alloc((size_t)MPAD * KTP * 2);         //  92.60 MB
  f16*   rad     = (f16*)alloc((size_t)MPAD * KEMB * 2 + (size_t)HD * KEMB * 2); // embed scratch
  f16*   Bcat    = (f16*)alloc((size_t)HD * KTOT * 2);          //   1.31 MB
  f16*   r2h     = (f16*)alloc((size_t)HD * KR2 * 2);           //   64 KB
  f16*   r1hb    = (f16*)alloc((size_t)128 * 32 * 2);           //    8 KB
  f16*   Wtp16   = (f16*)alloc((size_t)KTP * HD * 2);           //   1.18 MB
  f16*   WselfT16= (f16*)alloc((size_t)HD * HD * 2);            //   0.13 MB
  int*   rowptr  = (int*)alloc((size_t)(NNODE + 1) * 4);
  int*   deg     = (int*)alloc((size_t)NNODE * 4);
  int*   cursor  = (int*)alloc((size_t)NNODE * 4);
  int*   grp     = (int*)alloc((size_t)(NNODE + 2) * 4);
  int*   ngrp    = (int*)alloc(256);
  if (off > ws_size) return;

  // unions into rad (dead at those phases):
  f16*   xh      = rad;                              // embed phase
  f16*   WembT16 = rad + (size_t)MPAD * KEMB;

  hipMemsetAsync(deg, 0, (size_t)NNODE * 4, stream);
  hipMemsetAsync(cursor, 0, (size_t)NNODE * 4, stream);

  const int EB = (NEDGE + 255) / 256;
  deg_hist_kernel<<<EB, 256, 0, stream>>>(eidx, deg);
  scan_kernel<<<1, 256, 0, stream>>>(deg, rowptr);
  group_build_kernel<<<1, 256, 0, stream>>>(rowptr, grp, ngrp);
  edge_geom_kernel<<<EB, 256, 0, stream>>>(pos, shift, lat, eidx, batch,
                                           rowptr, cursor, sh_s, lens_s);

  // h0 = x @ W_embed via MFMA (no row permutation)
  convert_x_kernel<<<MPAD / 2, 256, 0, stream>>>(x, xh);
  convert_wemb_kernel<<<HD, KEMB, 0, stream>>>(Wemb, WembT16);
  {
    dim3 eg(MPAD / 64, HD / 128);
    gemm_nt_kernel<<<eg, 256, 0, stream>>>(xh, WembT16, hA, KEMB, HD, 0);
  }

  f16* hcur = hA;
  f16* hnxt = hB;
  dim3 fgrid(NRT, 2);                      // 628 blocks, fused GEMM
  dim3 wgrid(HD / 64, KTP / 128);          // (4, 18)
  for (int l = 0; l < NLAYER; ++l) {
    const float* r1l = r1 + (size_t)l * NBASIS * RHID;
    const float* b1l = b1 + (size_t)l * RHID;
    const float* r2l = r2 + (size_t)l * RHID * HD;
    const float* Wtp_l = Wtp + (size_t)l * NSH * HD * HD;
    const float* Wself_l = Wself + (size_t)l * HD * HD;
    const float* Wskip_l = Wskip + (size_t)l * HD * HD;

    prep_kernel<<<KTP + 768 + 1, 256, 0, stream>>>(Wtp_l, Wself_l, Wskip_l, r2l,
                                                   r1l, b1l,
                                                   Wtp16, WselfT16, Bcat, r2h, r1hb);
    gemm_nt_kernel<<<wgrid, 256, 0, stream>>>(WselfT16, Wtp16, Bcat, HD, KTOT, 1);

    radial_gather_kernel<<<4608, 256, 0, stream>>>(rowptr, grp, ngrp, lens_s,
                                                   sh_s, hcur, r1hb, r2h, T);
    gemm_fused_kernel<<<fgrid, 256, 0, stream>>>(T, hcur, Bcat, hnxt);
    f16* tmp = hcur; hcur = hnxt; hnxt = tmp;
  }

  node_out_fused_kernel<<<NGRAPH, 256, 0, stream>>>(hcur, Wout, batch, out);
}

// Round 8
// 668.876 us; speedup vs baseline: 1.4871x; 1.4871x over previous
//
#include <hip/hip_runtime.h>
#include <hip/hip_bf16.h>
#include <cstddef>
#include <cstdint>

#define NNODE  20000
#define MPAD   20096        // 314*64
#define NEDGE  240000
#define NGRAPH 200
#define DIN    118
#define HD     256
#define NBASIS 10
#define RHID   100
#define NLAYER 3
#define NSH    9
#define SHSTR  16           // sh row stride in f16 (32 B); [8]=Y8, [10..11]=src bits
#define KTP    (NSH * HD)   // 2304
#define KTOT   (KTP + HD)   // 2560
#define KR2    128          // padded radial K
#define KEMB   128          // padded embed K (118 -> 128)
#define NRT    (MPAD / 64)       // 314 row tiles

typedef _Float16 f16;
typedef _Float16 f16x2 __attribute__((ext_vector_type(2)));
typedef _Float16 f16x4 __attribute__((ext_vector_type(4)));
typedef _Float16 f16x8 __attribute__((ext_vector_type(8)));
typedef float    f32x4 __attribute__((ext_vector_type(4)));

__device__ __forceinline__ float gelu_tanh(float v) {
  float v3 = v * v * v;
  return 0.5f * v * (1.f + tanhf(0.7978845608028654f * (v + 0.044715f * v3)));
}

// async global->LDS 16B: LDS dest is wave-uniform base + lane*16 (HW rule)
__device__ __forceinline__ void gload16(const void* g, void* l) {
  __builtin_amdgcn_global_load_lds(
      (const __attribute__((address_space(1))) unsigned int*)g,
      (__attribute__((address_space(3))) unsigned int*)l, 16, 0, 0);
}

// within 64-group: physical row rho holds true column perm(rho)
__device__ __forceinline__ int perm64(int rho) {
  return (rho & ~63) | ((rho & 15) * 4 + ((rho >> 4) & 3));
}
__device__ __forceinline__ int inv_perm64(int n) {
  return (n & ~63) | (((n & 3) << 4) | ((n >> 2) & 15));
}

// ---------------- CSR build ----------------
__global__ void deg_hist_kernel(const int* __restrict__ ei, int* __restrict__ deg)
{
  int e = blockIdx.x * 256 + threadIdx.x;
  if (e >= NEDGE) return;
  atomicAdd(&deg[ei[NEDGE + e]], 1);
}

__global__ void scan_kernel(const int* __restrict__ deg, int* __restrict__ rowptr)
{
  __shared__ int part[256];
  int t = threadIdx.x;
  const int chunk = (NNODE + 255) / 256;
  int start = t * chunk;
  int end = min(start + chunk, NNODE);
  int s = 0;
  for (int i = start; i < end; ++i) s += deg[i];
  part[t] = s;
  __syncthreads();
  for (int off = 1; off < 256; off <<= 1) {
    int v = (t >= off) ? part[t - off] : 0;
    __syncthreads();
    part[t] += v;
    __syncthreads();
  }
  int run = (t == 0) ? 0 : part[t - 1];
  for (int i = start; i < end; ++i) { rowptr[i] = run; run += deg[i]; }
  if (t == 255) rowptr[NNODE] = run;
}

// -------- edge geometry + scatter into CSR (dst-sorted) position --------
__global__ void edge_geom_kernel(const float* __restrict__ pos,
                                 const float* __restrict__ shift,
                                 const float* __restrict__ lat,
                                 const int* __restrict__ ei,
                                 const int* __restrict__ batch,
                                 const int* __restrict__ rowptr,
                                 int* __restrict__ cursor,
                                 f16* __restrict__ sh_s,
                                 float* __restrict__ lens_s)
{
  int e = blockIdx.x * 256 + threadIdx.x;
  if (e >= NEDGE) return;
  int src = ei[e];
  int dst = ei[NEDGE + e];
  int b = batch[src];
  const float* L = lat + (size_t)b * 9;
  float s0 = shift[e * 3 + 0], s1 = shift[e * 3 + 1], s2 = shift[e * 3 + 2];
  float ev[3];
#pragma unroll
  for (int j = 0; j < 3; ++j)
    ev[j] = pos[dst * 3 + j] - pos[src * 3 + j] + s0 * L[j] + s1 * L[3 + j] + s2 * L[6 + j];
  float len = sqrtf(ev[0] * ev[0] + ev[1] * ev[1] + ev[2] * ev[2]);
  float inv = 1.f / (len + 1e-12f);
  float x = ev[0] * inv, y = ev[1] * inv, z = ev[2] * inv;
  const float c1 = 1.7320508075688772f;   // sqrt(3)
  const float c2 = 3.872983346207417f;    // sqrt(15)
  int p = atomicAdd(&cursor[dst], 1);
  int si = rowptr[dst] + p;
  f16* she = sh_s + (size_t)si * SHSTR;
  she[0] = (f16)1.f;
  she[1] = (f16)(c1 * x);
  she[2] = (f16)(c1 * y);
  she[3] = (f16)(c1 * z);
  she[4] = (f16)(c2 * x * y);
  she[5] = (f16)(c2 * y * z);
  she[6] = (f16)(1.1180339887498949f * (3.f * z * z - 1.f));  // sqrt(5)/2
  she[7] = (f16)(c2 * x * z);
  she[8] = (f16)(1.9364916731037085f * (x * x - y * y));      // sqrt(15)/2
  she[9] = (f16)0.f;
  *(int*)(she + 10) = src;            // src bits in slots 10-11 (4B-aligned)
  she[12] = (f16)0.f; she[13] = (f16)0.f; she[14] = (f16)0.f; she[15] = (f16)0.f;
  lens_s[si] = len;
}

// ---------------- merged per-layer weight prep ----------------
__global__ void prep_kernel(const float* __restrict__ Wtp_l,
                            const float* __restrict__ Wself_l,
                            const float* __restrict__ Wskip_l,
                            const float* __restrict__ r2l,
                            const float* __restrict__ r1l,
                            const float* __restrict__ b1l,
                            f16* __restrict__ Wtp16,
                            f16* __restrict__ WselfT16,
                            f16* __restrict__ Bcat,
                            f16* __restrict__ r2h,
                            f16* __restrict__ r1h)
{
  int b = blockIdx.x, t = threadIdx.x;
  if (b < KTP) {
    int i = b * 256 + t;
    Wtp16[i] = (f16)Wtp_l[i];
  } else if (b < KTP + 256) {
    int n = b - KTP;
    WselfT16[(size_t)n * HD + t] = (f16)(Wself_l[(size_t)t * HD + n] * 0.28867513459481287f);
  } else if (b < KTP + 512) {
    int rho = b - KTP - 256;            // physical (permuted) Bcat row
    int pcol = perm64(rho);             // true column it holds
    Bcat[(size_t)rho * KTOT + KTP + t] = (f16)Wskip_l[(size_t)t * HD + pcol];
  } else if (b < KTP + 768) {
    int rho = b - KTP - 512;
    if (t < KR2) {
      int p = perm64(rho);
      r2h[(size_t)rho * KR2 + t] = (t < RHID) ? (f16)r2l[(size_t)t * HD + p] : (f16)0.f;
    }
  } else {
    // r1h [128][32] f16, n-major: col j<NBASIS = r1[j][n]; j==NBASIS = bias; else 0.
#pragma unroll
    for (int u = 0; u < 16; ++u) {
      int idx = u * 256 + t;
      int n = idx >> 5, j = idx & 31;
      float v = 0.f;
      if (n < RHID) {
        if (j < NBASIS) v = r1l[(size_t)j * RHID + n];
        else if (j == NBASIS) v = b1l[n];
      }
      r1h[idx] = (f16)v;
    }
  }
}

// -------- embed conversions --------
__global__ void convert_x_kernel(const float* __restrict__ x, f16* __restrict__ xh)
{
  int i = blockIdx.x * 2 + (threadIdx.x >> 7);
  int k = threadIdx.x & 127;
  xh[(size_t)i * KEMB + k] = (i < NNODE && k < DIN) ? (f16)x[(size_t)i * DIN + k] : (f16)0.f;
}

__global__ void convert_wemb_kernel(const float* __restrict__ Wemb, f16* __restrict__ WembT16)
{
  int n = blockIdx.x, k = threadIdx.x;
  WembT16[(size_t)n * KEMB + k] = (k < DIN) ? (f16)Wemb[(size_t)k * HD + n] : (f16)0.f;
}

// small MFMA GEMM: C[M][ldc] = A[M][K] @ B^T, B n-major [N][K].
// permRows: store output row r at physical row inv_perm64(r) (for permuted Bcat).
__global__ __launch_bounds__(256) void gemm_nt_kernel(
    const f16* __restrict__ A, const f16* __restrict__ B,
    f16* __restrict__ C, int K, int ldc, int permRows)
{
  __shared__ __align__(16) f16 As[4][64][8];
  __shared__ __align__(16) f16 Bs[4][128][8];
  int t = threadIdx.x;
  int lane = t & 63, w = t >> 6;
  int row0 = blockIdx.x * 64;
  int n0 = blockIdx.y * 128;
  f32x4 acc[2][4];
#pragma unroll
  for (int i = 0; i < 2; ++i)
#pragma unroll
    for (int j = 0; j < 4; ++j) acc[i][j] = (f32x4){0.f, 0.f, 0.f, 0.f};
  int mq = (w & 1) * 32, nq = (w >> 1) * 64;
  for (int k0 = 0; k0 < K; k0 += 32) {
    {
      int row = t & 63, cc = t >> 6;
      *(uint4*)&As[cc][row][0] = *(const uint4*)(A + (size_t)(row0 + row) * K + k0 + cc * 8);
    }
#pragma unroll
    for (int u = 0; u < 2; ++u) {
      int idx = t + u * 256;
      int ch = idx >> 7, nn = idx & 127;
      *(uint4*)&Bs[ch][nn][0] = *(const uint4*)(B + (size_t)(n0 + nn) * K + k0 + ch * 8);
    }
    __syncthreads();
    int q = lane >> 4, r = lane & 15;
    f16x8 af[2], bfr[4];
#pragma unroll
    for (int i = 0; i < 2; ++i) af[i] = *(const f16x8*)&As[q][mq + i * 16 + r][0];
#pragma unroll
    for (int j = 0; j < 4; ++j) bfr[j] = *(const f16x8*)&Bs[q][nq + j * 16 + r][0];
#pragma unroll
    for (int i = 0; i < 2; ++i)
#pragma unroll
      for (int j = 0; j < 4; ++j)
        acc[i][j] = __builtin_amdgcn_mfma_f32_16x16x32_f16(af[i], bfr[j], acc[i][j], 0, 0, 0);
    __syncthreads();
  }
  int q4 = ((lane >> 4)) * 4, cl = lane & 15;
#pragma unroll
  for (int i = 0; i < 2; ++i)
#pragma unroll
    for (int rr = 0; rr < 4; ++rr) {
      int row = row0 + mq + i * 16 + q4 + rr;
      int orow = permRows ? inv_perm64(row) : row;
#pragma unroll
      for (int j = 0; j < 4; ++j)
        C[(size_t)orow * ldc + n0 + nq + j * 16 + cl] = (f16)acc[i][j][rr];
    }
}

// ------- hs[e,c] = radial[e,c] * h[src_e, c]  (R4 form, best measured) -------
#define RHSTR 136   // rhA stride (272 B)
__global__ __launch_bounds__(256) void radial_kernel(
    const float* __restrict__ lens_s,
    const f16* __restrict__ sh_s,     // for src ids (slots 10-11)
    const f16* __restrict__ h,        // current node features [NNODE][256]
    const f16* __restrict__ r1h,      // [128][32] f16 n-major (K-padded, bias j=10)
    const f16* __restrict__ r2h,      // [256][128] f16 perm64 rows
    f16* __restrict__ hs)             // out: rad*h[src]  [NEDGE][256]
{
  __shared__ __align__(16) f16 emb_s[64][40];     // 5 KB, stride 80 B
  __shared__ __align__(16) f16 rhA[64 * RHSTR];   // 17.4 KB
  __shared__ int srcs[64];
  int t = threadIdx.x;
  int lane = t & 63, w = t >> 6;
  int r = lane & 15, q = lane >> 4;
  int e0 = blockIdx.x * 64;

  // ---- src ids for this block's 64 edges
  if (t < 64) srcs[t] = *(const int*)(sh_s + (size_t)(e0 + t) * SHSTR + 10);

  // ---- basis: thread (w,lane) computes emb_s[lane][w*8 .. w*8+7]
  {
    float len = lens_s[e0 + lane];
    const float step = 5.f / 11.f;
    const float sq = 3.1622776601683795f;   // sqrt(10)
    f16x8 v;
#pragma unroll
    for (int kk = 0; kk < 8; ++kk) {
      int j = w * 8 + kk;
      float val = 0.f;
      if (j < NBASIS) {
        float d = (len - (float)(j + 1) * step) / step;
        val = (d > -1.f && d < 1.f) ? (__cosf(1.5707963267948966f * d) * sq) : 0.f;
      } else if (j == NBASIS) {
        val = 1.f;   // bias slot
      }
      v[kk] = (f16)val;
    }
    *(f16x8*)&emb_s[lane][w * 8] = v;
  }

  // ---- layer-2 B-frags (r2h, L2-resident), issued early
  int n0w = w * 64;
  f16x8 bfr[4][4];
#pragma unroll
  for (int j = 0; j < 4; ++j)
#pragma unroll
    for (int ks = 0; ks < 4; ++ks)
      bfr[j][ks] = *(const f16x8*)(r2h + (size_t)(n0w + j * 16 + r) * KR2 + ks * 32 + q * 8);

  // ---- layer-1 B-frags: wave w owns hidden n-tiles {2w, 2w+1}
  f16x8 b1f[2];
#pragma unroll
  for (int j = 0; j < 2; ++j)
    b1f[j] = *(const f16x8*)(r1h + (size_t)((2 * w + j) * 16 + r) * 32 + q * 8);

  __syncthreads();   // emb_s + srcs ready

  // ---- layer-1 MFMA: rh[64][128] = emb[64][32] @ r1h^T
  f32x4 acc1[4][2];
#pragma unroll
  for (int i = 0; i < 4; ++i)
#pragma unroll
    for (int j = 0; j < 2; ++j) acc1[i][j] = (f32x4){0.f, 0.f, 0.f, 0.f};
  {
    f16x8 a1f[4];
#pragma unroll
    for (int i = 0; i < 4; ++i)
      a1f[i] = *(const f16x8*)&emb_s[i * 16 + r][q * 8];
#pragma unroll
    for (int i = 0; i < 4; ++i)
#pragma unroll
      for (int j = 0; j < 2; ++j)
        acc1[i][j] = __builtin_amdgcn_mfma_f32_16x16x32_f16(a1f[i], b1f[j], acc1[i][j], 0, 0, 0);
  }

  // ---- silu -> rhA. value (i,j,rr): row=i*16+q*4+rr, col=(2w+j)*16+r
#pragma unroll
  for (int i = 0; i < 4; ++i)
#pragma unroll
    for (int j = 0; j < 2; ++j)
#pragma unroll
      for (int rr = 0; rr < 4; ++rr) {
        float s = acc1[i][j][rr];
        s = __fdividef(s, 1.f + __expf(-s));
        rhA[(i * 16 + q * 4 + rr) * RHSTR + (2 * w + j) * 16 + r] = (f16)s;
      }
  __syncthreads();   // rhA ready

  // ---- h[src] fragments for the epilogue: 16 coalesced f16x4 L2 loads,
  // issued BEFORE the layer-2 MFMA so their latency hides under it.
  f16x4 hv[4][4];
#pragma unroll
  for (int i = 0; i < 4; ++i)
#pragma unroll
    for (int rr = 0; rr < 4; ++rr) {
      int m = i * 16 + q * 4 + rr;
      hv[i][rr] = *(const f16x4*)(h + (size_t)srcs[m] * HD + n0w + r * 4);
    }

  // ---- layer-2 MFMA: radial[64,256] = rh[64,128] @ r2h_perm^T
  f32x4 acc[4][4];
#pragma unroll
  for (int i = 0; i < 4; ++i)
#pragma unroll
    for (int j = 0; j < 4; ++j) acc[i][j] = (f32x4){0.f, 0.f, 0.f, 0.f};
#pragma unroll
  for (int ks = 0; ks < 4; ++ks) {
    f16x8 af[4];
#pragma unroll
    for (int i = 0; i < 4; ++i)
      af[i] = *(const f16x8*)&rhA[(i * 16 + r) * RHSTR + ks * 32 + q * 8];
#pragma unroll
    for (int i = 0; i < 4; ++i)
#pragma unroll
      for (int j = 0; j < 4; ++j)
        acc[i][j] = __builtin_amdgcn_mfma_f32_16x16x32_f16(af[i], bfr[j][ks], acc[i][j], 0, 0, 0);
  }

  // stores: MFMA n-index j*16+r computed true col r*4+j -> multiply by h[src],
  // pack j as f16x4, coalesced
#pragma unroll
  for (int i = 0; i < 4; ++i)
#pragma unroll
    for (int rr = 0; rr < 4; ++rr) {
      int m = i * 16 + q * 4 + rr;
      f16x4 o;
#pragma unroll
      for (int j = 0; j < 4; ++j)
        o[j] = (f16)(acc[i][j][rr] * (float)hv[i][rr][j]);
      *(f16x4*)(hs + (size_t)(e0 + m) * HD + n0w + r * 4) = o;
    }
}

// ------- gather: T[n,a,c] = sum_{e->n} sh[e,a] * hs[e,c]  (R4 form) -------
__global__ __launch_bounds__(256) void gather2_kernel(
    const int* __restrict__ rowptr, const f16* __restrict__ hs,
    const f16* __restrict__ sh_s,
    f16* __restrict__ T)
{
  int t = threadIdx.x;
  int half = t >> 7, lc = t & 127;
  int base = blockIdx.x * 4;
  for (int s = 0; s < 2; ++s) {
    int n = base + s * 2 + half;
    int beg = rowptr[n], end = rowptr[n + 1];
    float a0[NSH], a1[NSH];
#pragma unroll
    for (int a = 0; a < NSH; ++a) { a0[a] = 0.f; a1[a] = 0.f; }
    int j = beg;
    for (; j + 2 <= end; j += 2) {
      const f16* she0 = sh_s + (size_t)j * SHSTR;
      const f16* she1 = she0 + SHSTR;
      f16x8 s80 = *(const f16x8*)she0;
      f16x8 s81 = *(const f16x8*)she1;
      float s8v0 = (float)she0[8];
      float s8v1 = (float)she1[8];
      f16x2 rv0 = *(const f16x2*)(hs + (size_t)j * HD + 2 * lc);
      f16x2 rv1 = *(const f16x2*)(hs + (size_t)(j + 1) * HD + 2 * lc);
      float p00 = (float)rv0[0];
      float p01 = (float)rv0[1];
      float p10 = (float)rv1[0];
      float p11 = (float)rv1[1];
#pragma unroll
      for (int a = 0; a < 8; ++a) {
        float sv0 = (float)s80[a], sv1 = (float)s81[a];
        a0[a] += sv0 * p00 + sv1 * p10;
        a1[a] += sv0 * p01 + sv1 * p11;
      }
      a0[8] += s8v0 * p00 + s8v1 * p10;
      a1[8] += s8v0 * p01 + s8v1 * p11;
    }
    if (j < end) {
      const f16* she = sh_s + (size_t)j * SHSTR;
      f16x8 s8 = *(const f16x8*)she;
      float s8v = (float)she[8];
      f16x2 rv = *(const f16x2*)(hs + (size_t)j * HD + 2 * lc);
      float p0 = (float)rv[0];
      float p1 = (float)rv[1];
#pragma unroll
      for (int a = 0; a < 8; ++a) {
        float sv = (float)s8[a];
        a0[a] += sv * p0; a1[a] += sv * p1;
      }
      a0[8] += s8v * p0; a1[8] += s8v * p1;
    }
    f16* Tn = T + (size_t)n * KTP + 2 * lc;
#pragma unroll
    for (int a = 0; a < NSH; ++a) {
      f16x2 o; o[0] = (f16)a0[a]; o[1] = (f16)a1[a];
      *(f16x2*)(Tn + a * HD) = o;
    }
  }
}

// ------- fused full-K MFMA GEMM + gelu epilogue -------
// v5: BK 32->64. R4 counters showed ~780 cyc per K-step (one load latency
// paid at each of 80 barrier drains) with occupancy GRID-limited (628 blocks
// = 2.45/CU; LDS/VGPR headroom). Halve the barrier count: 40 steps, 16
// MFMA + 12 ds_read per wave per barrier, dbuf LDS 48 KB (still not the
// occupancy limiter). 8-chunk involution swizzle (ch ^ row&7) keeps ds_reads
// conflict-free at no coalescing cost (global side carries the permutation).
#define GBM 64
#define GBN 128
#define BK  64
#define NKSTEP (KTOT / BK)    // 40
__global__ __launch_bounds__(256) void gemm_fused_kernel(
    const f16* __restrict__ A1,   // T [MPAD][2304]
    const f16* __restrict__ A2,   // h [MPAD][256]
    const f16* __restrict__ B,    // Bcat [256][2560] (n-major, perm64 rows)
    f16* __restrict__ C)          // h_next [MPAD][256]
{
  __shared__ __align__(16) f16 As[2][GBM][8][8];   // 16 KB
  __shared__ __align__(16) f16 Bs[2][GBN][8][8];   // 32 KB
  int t = threadIdx.x;
  int lane = t & 63, w = t >> 6;
  int row0 = blockIdx.x * GBM;
  int n0 = blockIdx.y * GBN;
  int mq = (w & 1) * 32, nq = (w >> 1) * 64;
  int q = lane >> 4, r = lane & 15;

  f32x4 acc[2][4];
#pragma unroll
  for (int i = 0; i < 2; ++i)
#pragma unroll
    for (int j = 0; j < 4; ++j) acc[i][j] = (f32x4){0.f, 0.f, 0.f, 0.f};

  auto stage = [&](int buf, int k0) {
    // A: 512 16B-slots ([row][ch] linear), 2/thread; global chunk = ch ^ (row&7)
#pragma unroll
    for (int u = 0; u < 2; ++u) {
      int idx = u * 256 + t;
      int row = idx >> 3, chg = (idx & 7) ^ (row & 7);
      const f16* ga = (k0 < KTP)
          ? (A1 + (size_t)(row0 + row) * KTP + k0 + chg * 8)
          : (A2 + (size_t)(row0 + row) * HD + (k0 - KTP) + chg * 8);
      gload16(ga, &As[buf][0][0][0] + (size_t)(u * 256 + w * 64) * 8);
    }
    // B: 1024 slots, 4/thread
#pragma unroll
    for (int u = 0; u < 4; ++u) {
      int idx = u * 256 + t;
      int row = idx >> 3, chg = (idx & 7) ^ (row & 7);
      const f16* gb = B + (size_t)(n0 + row) * KTOT + k0 + chg * 8;
      gload16(gb, &Bs[buf][0][0][0] + (size_t)(u * 256 + w * 64) * 8);
    }
  };

  stage(0, 0);
  __syncthreads();   // buf0 ready

  int cur = 0;
  for (int s = 0; s < NKSTEP; ++s) {
    if (s + 1 < NKSTEP) stage(cur ^ 1, (s + 1) * BK);
#pragma unroll
    for (int kk = 0; kk < 2; ++kk) {
      f16x8 af[2], bfr[4];
#pragma unroll
      for (int i = 0; i < 2; ++i) {
        int row = mq + i * 16 + r;
        af[i] = *(const f16x8*)&As[cur][row][(kk * 4 + q) ^ (row & 7)][0];
      }
#pragma unroll
      for (int j = 0; j < 4; ++j) {
        int row = nq + j * 16 + r;
        bfr[j] = *(const f16x8*)&Bs[cur][row][(kk * 4 + q) ^ (row & 7)][0];
      }
#pragma unroll
      for (int i = 0; i < 2; ++i)
#pragma unroll
        for (int j = 0; j < 4; ++j)
          acc[i][j] = __builtin_amdgcn_mfma_f32_16x16x32_f16(af[i], bfr[j], acc[i][j], 0, 0, 0);
    }
    __syncthreads();   // drains vmcnt: stage(s+1) landed; reads of buf[cur] done
    cur ^= 1;
  }

  // permuted-B gelu epilogue: MFMA n-index j*16+cl -> true col cl*4+j
  int q4 = (lane >> 4) * 4, cl = lane & 15;
#pragma unroll
  for (int i = 0; i < 2; ++i)
#pragma unroll
    for (int rr = 0; rr < 4; ++rr) {
      int row = row0 + mq + i * 16 + q4 + rr;   // MPAD-padded: no guard
      f16x4 o;
#pragma unroll
      for (int j = 0; j < 4; ++j) o[j] = (f16)gelu_tanh(acc[i][j][rr]);
      *(f16x4*)(C + (size_t)row * HD + n0 + nq + cl * 4) = o;
    }
}

// ---------------- node_out fused with graph mean (no atomics) ----------------
__global__ __launch_bounds__(256) void node_out_fused_kernel(
    const f16* __restrict__ h,
    const float* __restrict__ Wout,
    const int* __restrict__ batch,
    float* __restrict__ out)
{
  __shared__ float red[256];
  int g = blockIdx.x;
  int t = threadIdx.x;
  int lo = 0, hi = NNODE;
  while (lo < hi) { int mid = (lo + hi) >> 1; if (batch[mid] < g) lo = mid + 1; else hi = mid; }
  int start = lo;
  hi = NNODE;
  while (lo < hi) { int mid = (lo + hi) >> 1; if (batch[mid] < g + 1) lo = mid + 1; else hi = mid; }
  int end = lo;
  int half = t >> 7, lc = t & 127;
  float a0 = 0.f, a1 = 0.f;
  for (int n = start + half; n < end; n += 2) {
    f16x2 v = *(const f16x2*)(h + (size_t)n * HD + 2 * lc);
    a0 += (float)v[0];
    a1 += (float)v[1];
  }
  red[t] = a0 * Wout[2 * lc] + a1 * Wout[2 * lc + 1];
  for (int off = 128; off > 0; off >>= 1) {
    __syncthreads();
    if (t < off) red[t] += red[t + off];
  }
  if (t == 0) out[g] = red[0] / fmaxf((float)(end - start), 1.f);
}

// ---------------- host launch ----------------
extern "C" void kernel_launch(void* const* d_in, const int* in_sizes, int n_in,
                              void* d_out, int out_size, void* d_ws, size_t ws_size,
                              hipStream_t stream)
{
  (void)in_sizes; (void)n_in; (void)out_size;
  const float* x     = (const float*)d_in[0];
  const float* pos   = (const float*)d_in[1];
  const float* shift = (const float*)d_in[2];
  const float* lat   = (const float*)d_in[3];
  const float* Wemb  = (const float*)d_in[4];
  const float* r1    = (const float*)d_in[5];
  const float* b1    = (const float*)d_in[6];
  const float* r2    = (const float*)d_in[7];
  const float* Wtp   = (const float*)d_in[8];
  const float* Wself = (const float*)d_in[9];
  const float* Wskip = (const float*)d_in[10];
  const float* Wout  = (const float*)d_in[11];
  const int*   eidx  = (const int*)d_in[12];
  const int*   batch = (const int*)d_in[13];
  float* out = (float*)d_out;

  char* ws = (char*)d_ws;
  size_t off = 0;
  auto alloc = [&](size_t bytes) -> char* {
    char* p = ws + off;
    off += (bytes + 255) & ~(size_t)255;
    return p;
  };
  f16*   sh_s    = (f16*)alloc((size_t)NEDGE * SHSTR * 2);      //   7.68 MB
  float* lens_s  = (float*)alloc((size_t)NEDGE * 4);            //   0.96 MB
  f16*   hA      = (f16*)alloc((size_t)MPAD * HD * 2);          //  10.29 MB
  f16*   hB      = (f16*)alloc((size_t)MPAD * HD * 2);          //  10.29 MB
  f16*   T       = (f16*)alloc((size_t)MPAD * KTP * 2);         //  92.60 MB
  f16*   rad     = (f16*)alloc((size_t)NEDGE * HD * 2);         // 122.88 MB (hs)
  f16*   Bcat    = (f16*)alloc((size_t)HD * KTOT * 2);          //   1.31 MB
  f16*   r2h     = (f16*)alloc((size_t)HD * KR2 * 2);           //   64 KB
  f16*   r1hb    = (f16*)alloc((size_t)128 * 32 * 2);           //    8 KB
  f16*   Wtp16   = (f16*)alloc((size_t)KTP * HD * 2);           //   1.18 MB
  f16*   WselfT16= (f16*)alloc((size_t)HD * HD * 2);            //   0.13 MB
  int*   rowptr  = (int*)alloc((size_t)(NNODE + 1) * 4);
  int*   deg     = (int*)alloc((size_t)NNODE * 4);
  int*   cursor  = (int*)alloc((size_t)NNODE * 4);
  if (off > ws_size) return;

  // unions into rad (dead at those phases):
  f16*   xh      = rad;                              // embed phase
  f16*   WembT16 = rad + (size_t)MPAD * KEMB;

  hipMemsetAsync(deg, 0, (size_t)NNODE * 4, stream);
  hipMemsetAsync(cursor, 0, (size_t)NNODE * 4, stream);

  const int EB = (NEDGE + 255) / 256;
  deg_hist_kernel<<<EB, 256, 0, stream>>>(eidx, deg);
  scan_kernel<<<1, 256, 0, stream>>>(deg, rowptr);
  edge_geom_kernel<<<EB, 256, 0, stream>>>(pos, shift, lat, eidx, batch,
                                           rowptr, cursor, sh_s, lens_s);

  // h0 = x @ W_embed via MFMA (no row permutation)
  convert_x_kernel<<<MPAD / 2, 256, 0, stream>>>(x, xh);
  convert_wemb_kernel<<<HD, KEMB, 0, stream>>>(Wemb, WembT16);
  {
    dim3 eg(MPAD / 64, HD / 128);
    gemm_nt_kernel<<<eg, 256, 0, stream>>>(xh, WembT16, hA, KEMB, HD, 0);
  }

  f16* hcur = hA;
  f16* hnxt = hB;
  dim3 fgrid(NRT, 2);                      // 628 blocks, fused GEMM
  dim3 wgrid(HD / 64, KTP / 128);          // (4, 18)
  for (int l = 0; l < NLAYER; ++l) {
    const float* r1l = r1 + (size_t)l * NBASIS * RHID;
    const float* b1l = b1 + (size_t)l * RHID;
    const float* r2l = r2 + (size_t)l * RHID * HD;
    const float* Wtp_l = Wtp + (size_t)l * NSH * HD * HD;
    const float* Wself_l = Wself + (size_t)l * HD * HD;
    const float* Wskip_l = Wskip + (size_t)l * HD * HD;

    prep_kernel<<<KTP + 768 + 1, 256, 0, stream>>>(Wtp_l, Wself_l, Wskip_l, r2l,
                                                   r1l, b1l,
                                                   Wtp16, WselfT16, Bcat, r2h, r1hb);
    gemm_nt_kernel<<<wgrid, 256, 0, stream>>>(WselfT16, Wtp16, Bcat, HD, KTOT, 1);

    radial_kernel<<<NEDGE / 64, 256, 0, stream>>>(lens_s, sh_s, hcur, r1hb, r2h, rad);
    gather2_kernel<<<NNODE / 4, 256, 0, stream>>>(rowptr, rad, sh_s, T);
    gemm_fused_kernel<<<fgrid, 256, 0, stream>>>(T, hcur, Bcat, hnxt);
    f16* tmp = hcur; hcur = hnxt; hnxt = tmp;
  }

  node_out_fused_kernel<<<NGRAPH, 256, 0, stream>>>(hcur, Wout, batch, out);
}